// Round 3
// baseline (751.879 us; speedup 1.0000x reference)
//
#include <hip/hip_runtime.h>
#include <hip/hip_cooperative_groups.h>
#include <stdint.h>
#include <stddef.h>

// IEEE-exact ops, no FMA contraction: binary labels must match the reference
// exactly (absmax threshold 2e-2 on a {0,1} output).
#pragma clang fp contract(off)

namespace cg = cooperative_groups;

#define HH 512
#define WW 512
#define HW_ 262144             // H*W
#define FEAT_BSTRIDE (256*HW_) // feature batch stride (C=256)

// normalize+quantize exactly like the reference:
// clip(floor((f-mn)/(mx-mn+1e-12)*255), 0, 255)
__device__ __forceinline__ float quantf(float f, float mn, float denom) {
  float v = (f - mn) / denom * 255.0f;
  v = floorf(v);
  return fminf(fmaxf(v, 0.0f), 255.0f);
}

// trimap geometry: bh=bw=51, center rows/cols [230,281)
__device__ __forceinline__ bool is_center(int y, int x) {
  return (y >= 230) & (y < 281) & (x >= 230) & (x < 281);
}
__device__ __forceinline__ bool is_border(int y, int x) {
  return (y < 51) | (y >= 461) | (x < 51) | (x >= 461);
}

// One cooperative kernel: 256 blocks (128 per batch) x 256 threads.
// Each thread owns 8 pixels (p = blk*2048 + tid + j*256) for the whole
// kernel; quantized RGB lives in VGPRs across all 5 ICM iterations. Only
// alpha (u8, double-buffered) and the int reduction partials go through
// global memory. All cross-stage dependencies via grid.sync().
__global__ __launch_bounds__(256) void k_fused(
    const float* __restrict__ feat, const int* __restrict__ mask,
    uint8_t* __restrict__ aA, uint8_t* __restrict__ aB,
    float2* __restrict__ mm, int4* __restrict__ totals,
    int4* __restrict__ slots, float* __restrict__ out)
{
  cg::grid_group grid = cg::this_grid();
  const int blk = blockIdx.x, tid = threadIdx.x;
  const int b = blk >> 7;                 // batch
  const float* fb = feat + (size_t)b * FEAT_BSTRIDE;
  const int pbase = blk * 2048 + tid;

  __shared__ float smn[256], smx[256];    // 2 KB
  __shared__ int red[256][8];             // 8 KB
  __shared__ float fmv[3], bmv[3];

  // ---- stage 0: load my 8 px x 3 channels (coalesced), minmax partial ----
  float rq[8], gq[8], bq[8];
  float mn = 3.4e38f, mx = -3.4e38f;
#pragma unroll
  for (int j = 0; j < 8; j++) {
    int pb = (pbase + j * 256) & (HW_ - 1);
    float r = fb[pb], g = fb[HW_ + pb], bl = fb[2 * HW_ + pb];
    rq[j] = r; gq[j] = g; bq[j] = bl;
    mn = fminf(mn, fminf(fminf(r, g), bl));
    mx = fmaxf(mx, fmaxf(fmaxf(r, g), bl));
  }
  smn[tid] = mn; smx[tid] = mx;
  __syncthreads();
  for (int s = 128; s >= 1; s >>= 1) {
    if (tid < s) {
      smn[tid] = fminf(smn[tid], smn[tid + s]);
      smx[tid] = fmaxf(smx[tid], smx[tid + s]);
    }
    __syncthreads();
  }
  if (tid == 0) mm[blk] = make_float2(smn[0], smx[0]);
  grid.sync();

  // ---- cross-block minmax for my batch (redundant per block) ----
  if (tid < 128) { float2 v = mm[b * 128 + tid]; smn[tid] = v.x; smx[tid] = v.y; }
  __syncthreads();
  for (int s = 64; s >= 1; s >>= 1) {
    if (tid < s) {
      smn[tid] = fminf(smn[tid], smn[tid + s]);
      smx[tid] = fmaxf(smx[tid], smx[tid + s]);
    }
    __syncthreads();
  }
  mn = smn[0];
  const float denom = (smx[0] - mn) + 1e-12f;  // f32, matches reference

  // quantize in registers (exact integers 0..255 stored as floats)
#pragma unroll
  for (int j = 0; j < 8; j++) {
    rq[j] = quantf(rq[j], mn, denom);
    gq[j] = quantf(gq[j], mn, denom);
    bq[j] = quantf(bq[j], mn, denom);
  }

  // ---- stage 1: initial alpha from mask+trimap; slot0 + totals partials ----
  {
    int a0 = 0, a1 = 0, a2 = 0, a3 = 0, t0 = 0, t1 = 0, t2 = 0;
#pragma unroll
    for (int j = 0; j < 8; j++) {
      int p = pbase + j * 256;
      int pb = p & (HW_ - 1);
      int y = pb >> 9, x = pb & 511;
      int aj;
      if (is_center(y, x)) aj = 1;
      else if (is_border(y, x)) aj = 0;
      else aj = (mask[p] == 1) ? 1 : 0;
      aA[p] = (uint8_t)aj;
      int ri = (int)rq[j], gi = (int)gq[j], bi = (int)bq[j];
      a0 += ri * aj; a1 += gi * aj; a2 += bi * aj; a3 += aj;
      t0 += ri; t1 += gi; t2 += bi;
    }
    red[tid][0] = a0; red[tid][1] = a1; red[tid][2] = a2; red[tid][3] = a3;
    red[tid][4] = t0; red[tid][5] = t1; red[tid][6] = t2; red[tid][7] = 0;
    __syncthreads();
    for (int s = 128; s >= 1; s >>= 1) {
      if (tid < s) {
#pragma unroll
        for (int j = 0; j < 7; j++) red[tid][j] += red[tid + s][j];
      }
      __syncthreads();
    }
    if (tid == 0) {
      slots[blk]  = make_int4(red[0][0], red[0][1], red[0][2], red[0][3]);
      totals[blk] = make_int4(red[0][4], red[0][5], red[0][6], 0);
    }
  }
  grid.sync();

  // ---- stages 2..6: five ICM iterations ----
  uint8_t* ain = aA;
  uint8_t* aout = aB;
  for (int k = 0; k < 5; k++) {
    // redundant per-block deterministic reduce of my batch's 128 partials
    if (tid < 128) {
      int4 s4 = slots[k * 256 + b * 128 + tid];
      int4 t4 = totals[b * 128 + tid];
      red[tid][0] = s4.x; red[tid][1] = s4.y; red[tid][2] = s4.z; red[tid][3] = s4.w;
      red[tid][4] = t4.x; red[tid][5] = t4.y; red[tid][6] = t4.z; red[tid][7] = 0;
    }
    __syncthreads();
    for (int s = 64; s >= 1; s >>= 1) {
      if (tid < s) {
#pragma unroll
        for (int j = 0; j < 7; j++) red[tid][j] += red[tid + s][j];
      }
      __syncthreads();
    }
    if (tid == 0) {
      int cnt = red[0][3];
      float fden = (float)cnt + 1e-6f;
      float bden = (float)(HW_ - cnt) + 1e-6f;
#pragma unroll
      for (int c = 0; c < 3; c++) {
        fmv[c] = (float)red[0][c] / fden;                   // fg_mean
        bmv[c] = (float)(red[0][4 + c] - red[0][c]) / bden; // bg_mean
      }
    }
    __syncthreads();
    float f0 = fmv[0], f1 = fmv[1], f2 = fmv[2];
    float g0 = bmv[0], g1 = bmv[1], g2 = bmv[2];

    int c0 = 0, c1 = 0, c2 = 0, c3 = 0;
#pragma unroll
    for (int j = 0; j < 8; j++) {
      int p = pbase + j * 256;
      int pb = p & (HW_ - 1);
      int y = pb >> 9, x = pb & 511;
      float i0 = rq[j], i1 = gq[j], i2 = bq[j];
      // 4-neighbor mean with edge replication (stays within batch: y,x from pb)
      int up = ain[p - (y > 0 ? WW : 0)];
      int dn = ain[p + (y < HH - 1 ? WW : 0)];
      int lf = ain[p - (x > 0 ? 1 : 0)];
      int rt = ain[p + (x < WW - 1 ? 1 : 0)];
      float nb = (float)(((up + dn) + lf) + rt) * 0.25f;    // exact in f32
      float pr = 50.0f * ((2.0f * nb) - 1.0f);              // exact in f32
      float d0 = i0 - f0, d1 = i1 - f1, d2 = i2 - f2;
      float df = ((d0 * d0) + (d1 * d1)) + (d2 * d2);
      float u0 = i0 - g0, u1 = i1 - g1, u2 = i2 - g2;
      float db = ((u0 * u0) + (u1 * u1)) + (u2 * u2);
      float sc = (db - df) + pr;
      int aj;
      if (is_center(y, x)) aj = 1;          // fixed FG
      else if (is_border(y, x)) aj = 0;     // fixed BG
      else aj = (sc > 0.0f) ? 1 : 0;
      if (k == 4) out[p] = (float)aj;       // final labels, float32
      else aout[p] = (uint8_t)aj;
      c0 += (int)i0 * aj; c1 += (int)i1 * aj; c2 += (int)i2 * aj; c3 += aj;
    }

    if (k < 4) {
      red[tid][0] = c0; red[tid][1] = c1; red[tid][2] = c2; red[tid][3] = c3;
      __syncthreads();
      for (int s = 128; s >= 1; s >>= 1) {
        if (tid < s) {
#pragma unroll
          for (int j = 0; j < 4; j++) red[tid][j] += red[tid + s][j];
        }
        __syncthreads();
      }
      if (tid == 0)
        slots[(k + 1) * 256 + blk] = make_int4(red[0][0], red[0][1], red[0][2], red[0][3]);
      uint8_t* tmp = ain; ain = aout; aout = tmp;
      grid.sync();
    }
  }
}

extern "C" void kernel_launch(void* const* d_in, const int* in_sizes, int n_in,
                              void* d_out, int out_size, void* d_ws, size_t ws_size,
                              hipStream_t stream) {
  const float* feat = (const float*)d_in[0];   // (2,256,512,512) f32
  const int*   mask = (const int*)d_in[1];     // (2,512,512) i32
  float* out = (float*)d_out;                  // (2,512,512) f32

  // ws layout (~1.1 MB; every buffer written before read each launch):
  char* ws = (char*)d_ws;
  uint8_t* aA     = (uint8_t*)(ws);             // 524288
  uint8_t* aB     = (uint8_t*)(ws + 524288);    // 524288
  float2*  mm     = (float2*)(ws + 1048576);    // 256 * 8B
  int4*    totals = (int4*)(ws + 1050624);      // 256 * 16B
  int4*    slots  = (int4*)(ws + 1054720);      // 6*256*16B (slot5 unused)

  void* args[] = {(void*)&feat, (void*)&mask, (void*)&aA, (void*)&aB,
                  (void*)&mm, (void*)&totals, (void*)&slots, (void*)&out};
  hipLaunchCooperativeKernel((const void*)k_fused, dim3(256), dim3(256),
                             args, 0, stream);
}